// Round 2
// baseline (115.976 us; speedup 1.0000x reference)
//
#include <hip/hip_runtime.h>

// Problem: B=2, DIM=512, NUM_HEADS=1, tokens TOK=256 (16x16 window, w=1).
// Pipeline (4 kernels, no K-split, no combine):
//   prep      : convert qkv_w, x, proj_w -> bf16 hi/lo planes, MFMA-frag-tiled
//   gemm_frag : barrier-free LDS-free bf16 split-3 MFMA GEMM (qkv), fp32 out
//   attn_f32  : fused per-channel attention; epilogue writes aout as frag-tiled
//               hi/lo planes (proj's B operand, no fp32 aout ever materialized)
//   gemm_frag : proj GEMM reading prepped proj_w planes + attn's aout planes,
//               adds proj bias, writes final output directly.
//
// Frag-tiled layout for a matrix consumed as an MFMA operand (A: [M][K] rows=m;
// B: logical [K][N] consumed as [n][k]):  idx(r, k) = ((r/16)*(K/8) + k/8)*128
// + (r%16)*8 + (k%8).  A wave's fragment load (lr=lane&15 row, lg=lane>>4
// k-chunk) is 64 lanes x 16B = one contiguous 1 KiB block -> perfect coalesce.
//
// ws layout: ushort planes first, then fp32 qkv buffer.
//   WqAh 0        WqAl 786432    (qkv_w planes, 1536x512)
//   XBh  1572864  XBl  1835008   (x planes,     2x[256n][512k])
//   WpAh 2097152  WpAl 2359296   (proj_w planes, 512x512)
//   AoBh 2621440  AoBl 2883584   (aout planes,  2x[256n][512k])
//   qkvf32 at float offset 1572864 (byte 6291456): [2][1536][256] fp32
// total 9.4 MB of d_ws.

#define TOK    256
#define KDIM   512
#define K8     64                   // KDIM/8
#define LOG2E  1.4426950408889634f
#define SCALE  0.04419417382415922f // 512^{-1/2}

#define OFF_WQAH 0
#define OFF_WQAL 786432
#define OFF_XBH  1572864
#define OFF_XBL  1835008
#define OFF_WPAH 2097152
#define OFF_WPAL 2359296
#define OFF_AOBH 2621440
#define OFF_AOBL 2883584
#define OFF_QKVF 1572864            // float offset

#define EXP2(x) __builtin_amdgcn_exp2f(x)

typedef __attribute__((ext_vector_type(8))) short short8_t;  // 8 bf16 (4 VGPR)
typedef __attribute__((ext_vector_type(4))) float f32x4;     // MFMA acc

// round-to-nearest-even fp32 -> bf16 bits
__device__ __forceinline__ unsigned short f2bf(float x) {
    unsigned int u = __float_as_uint(x);
    u += 0x7fffu + ((u >> 16) & 1u);
    return (unsigned short)(u >> 16);
}
__device__ __forceinline__ float bf2f(unsigned short h) {
    return __uint_as_float((unsigned int)h << 16);
}

__device__ __forceinline__ void cvt8(const float* v, unsigned short* hq,
                                     unsigned short* lq) {
#pragma unroll
    for (int j = 0; j < 8; ++j) {
        const unsigned short h = f2bf(v[j]);
        hq[j] = h;
        lq[j] = f2bf(v[j] - bf2f(h));
    }
}

// ---------------------------------------------------------------------------
// prep: one thread per 8-wide k-chunk. 163,840 threads = 640 blocks x 256.
//   job0 [0,98304):      qkv_w [1536][512] -> WqAh/WqAl (A-frag layout)
//   job1 [98304,131072): x [2][512][256]   -> XBh/XBl   (B-frag layout, n=tok)
//   job2 [131072,163840): proj_w [512][512] -> WpAh/WpAl
// ---------------------------------------------------------------------------
__global__ __launch_bounds__(256)
void prep(const float* __restrict__ qkv_w, const float* __restrict__ x,
          const float* __restrict__ proj_w, unsigned short* __restrict__ U)
{
    const int id = blockIdx.x * 256 + threadIdx.x;
    alignas(16) unsigned short hq[8], lq[8];
    float v[8];

    if (id < 98304) {                       // qkv_w
        const int m = id >> 6, kc = id & 63;
        const float* s = qkv_w + (size_t)m * KDIM + kc * 8;
#pragma unroll
        for (int j = 0; j < 8; ++j) v[j] = s[j];
        cvt8(v, hq, lq);
        const size_t o = ((size_t)(m >> 4) * K8 + kc) * 128 + (size_t)(m & 15) * 8;
        *(uint4*)(U + OFF_WQAH + o) = *(const uint4*)hq;
        *(uint4*)(U + OFF_WQAL + o) = *(const uint4*)lq;
    } else if (id < 131072) {               // x (transpose k<->n into B-frag)
        const int rid = id - 98304;
        const int n = rid & 255, kc = (rid >> 8) & 63, b = rid >> 14;
        const float* s = x + ((size_t)b * KDIM + kc * 8) * TOK + n;
#pragma unroll
        for (int j = 0; j < 8; ++j) v[j] = s[(size_t)j * TOK];
        cvt8(v, hq, lq);
        const size_t o = (((size_t)b * 16 + (n >> 4)) * K8 + kc) * 128
                         + (size_t)(n & 15) * 8;
        *(uint4*)(U + OFF_XBH + o) = *(const uint4*)hq;
        *(uint4*)(U + OFF_XBL + o) = *(const uint4*)lq;
    } else if (id < 163840) {               // proj_w
        const int rid = id - 131072;
        const int m = rid >> 6, kc = rid & 63;
        const float* s = proj_w + (size_t)m * KDIM + kc * 8;
#pragma unroll
        for (int j = 0; j < 8; ++j) v[j] = s[j];
        cvt8(v, hq, lq);
        const size_t o = ((size_t)(m >> 4) * K8 + kc) * 128 + (size_t)(m & 15) * 8;
        *(uint4*)(U + OFF_WPAH + o) = *(const uint4*)hq;
        *(uint4*)(U + OFF_WPAL + o) = *(const uint4*)lq;
    }
}

// ---------------------------------------------------------------------------
// Barrier-free fragment GEMM: 1 wave (64 thr) per block, wave tile 32m x 64n.
// C[b][row][tok] = A[row][:] . B[b][:][tok] (+bias), split-3 bf16 MFMA, K=512.
// All fragments loaded directly from frag-tiled global planes (L2-resident),
// 1-step register prefetch, fully unrolled, zero LDS / zero syncthreads.
// Grid: (Mtot/32, TOK/64, 2).
// ---------------------------------------------------------------------------
template<bool BIAS>
__global__ __launch_bounds__(64)
void gemm_frag(const unsigned short* __restrict__ Ah,
               const unsigned short* __restrict__ Al,
               const unsigned short* __restrict__ Bh,
               const unsigned short* __restrict__ Bl,
               const float* __restrict__ bias,
               float* __restrict__ Cout, int Mtot)
{
    const int t   = threadIdx.x;
    const int lr  = t & 15;          // frag row (A) / col (B) / col (D)
    const int lg  = t >> 4;          // k-chunk group / D row-quad
    const int mt0 = blockIdx.x * 2;  // two 16-row m tiles
    const int nt0 = blockIdx.y * 4;  // four 16-col n tiles
    const int b   = blockIdx.z;

    f32x4 acc[2][4];
#pragma unroll
    for (int mi = 0; mi < 2; ++mi)
#pragma unroll
        for (int ni = 0; ni < 4; ++ni)
            acc[mi][ni] = (f32x4){0.f, 0.f, 0.f, 0.f};

    short8_t ah[2][2], al[2][2], bh[2][4], bl[2][4];

#define LDF(S, P) do {                                                        \
        const int kc_ = (S) * 4 + lg;                                         \
        _Pragma("unroll")                                                     \
        for (int mi = 0; mi < 2; ++mi) {                                      \
            const size_t o_ = ((size_t)(mt0 + mi) * K8 + kc_) * 128           \
                              + (size_t)lr * 8;                               \
            ah[P][mi] = *(const short8_t*)(Ah + o_);                          \
            al[P][mi] = *(const short8_t*)(Al + o_);                          \
        }                                                                     \
        _Pragma("unroll")                                                     \
        for (int ni = 0; ni < 4; ++ni) {                                      \
            const size_t o_ = (((size_t)b * 16 + nt0 + ni) * K8 + kc_) * 128  \
                              + (size_t)lr * 8;                               \
            bh[P][ni] = *(const short8_t*)(Bh + o_);                          \
            bl[P][ni] = *(const short8_t*)(Bl + o_);                          \
        }                                                                     \
    } while (0)

    LDF(0, 0);
#pragma unroll
    for (int s = 0; s < 16; ++s) {           // 16 K-steps of 32
        const int p = s & 1;
        if (s + 1 < 16) LDF(s + 1, p ^ 1);   // prefetch next step's frags
#pragma unroll
        for (int mi = 0; mi < 2; ++mi)
#pragma unroll
            for (int ni = 0; ni < 4; ++ni) {
                acc[mi][ni] = __builtin_amdgcn_mfma_f32_16x16x32_bf16(
                    ah[p][mi], bh[p][ni], acc[mi][ni], 0, 0, 0);
                acc[mi][ni] = __builtin_amdgcn_mfma_f32_16x16x32_bf16(
                    al[p][mi], bh[p][ni], acc[mi][ni], 0, 0, 0);
                acc[mi][ni] = __builtin_amdgcn_mfma_f32_16x16x32_bf16(
                    ah[p][mi], bl[p][ni], acc[mi][ni], 0, 0, 0);
            }
    }
#undef LDF

    // epilogue: D frag (col=lr, row=lg*4+r) -> global, optional bias
#pragma unroll
    for (int mi = 0; mi < 2; ++mi)
#pragma unroll
        for (int r = 0; r < 4; ++r) {
            const int row = (mt0 + mi) * 16 + lg * 4 + r;
            const float pb = BIAS ? bias[row] : 0.f;
#pragma unroll
            for (int ni = 0; ni < 4; ++ni) {
                const int col = (nt0 + ni) * 16 + lr;
                Cout[((size_t)b * Mtot + row) * TOK + col] = acc[mi][ni][r] + pb;
            }
        }
}

// ---------------------------------------------------------------------------
// Fused per-channel attention. Block = 256 threads handles (b, d0..d0+1).
// Reads the unsplit fp32 qkv buffer [b][1536][256]; adds qkv bias inline.
// bias[h,g] = tab[r(h)-r(g)+30], r(h)=(h>>4)+(h&15): 61 distinct values,
// replicated into brow[31][258] (2-bank step, conflict-free float2 reads).
// Scores bounded (~1.1) -> no max-subtraction; g-half partials merge additively.
// Epilogue writes aout as hi/lo bf16 planes in proj's B-frag layout.
// ---------------------------------------------------------------------------
__global__ __launch_bounds__(256)
void attn_f32(const float* __restrict__ qkvf, const float* __restrict__ qkv_b,
              const float* __restrict__ rpb,
              unsigned short* __restrict__ aoh, unsigned short* __restrict__ aol)
{
    __shared__ float ks_[2][TOK];      // k * scale * log2e (incl. qkv bias)
    __shared__ float vs_[2][TOK];      // v (incl. qkv bias)
    __shared__ float tab2[64];         // rpb gathered, * log2e
    __shared__ float brow[31][258];    // bias rows, stride 258 (2-bank step)
    __shared__ float lpart[2][TOK];
    __shared__ float apart[2][TOK];

    const int t  = threadIdx.x;
    const int b  = blockIdx.y;
    const int d0 = blockIdx.x * 2;
    const float* q0 = qkvf + (size_t)b * (1536 * TOK);

    // phase 0: bias table (61 values)
    if (t < 61) {
        const int rel = t - 30;
        tab2[t] = rpb[rel < 0 ? rel + 961 : rel] * LOG2E;
    }
    // phase 1: stage k and v rows for the 2 channels (+qkv bias)
    {
        const int sel = t >> 7;          // 0: k, 1: v
        const int row = (t >> 6) & 1;    // dl
        const int g4  = (t & 63) * 4;
        const int o   = (sel ? 1024 : 512) + d0 + row;
        const float bb = qkv_b[o];
        float4 v = *(const float4*)(q0 + (size_t)o * TOK + g4);
        v.x += bb; v.y += bb; v.z += bb; v.w += bb;
        if (sel == 0) {
            const float s = SCALE * LOG2E;
            v.x *= s; v.y *= s; v.z *= s; v.w *= s;
            *(float4*)&ks_[row][g4] = v;
        } else {
            *(float4*)&vs_[row][g4] = v;
        }
    }
    __syncthreads();
    // phase 2: replicate bias into 31 rows x 256 g
    {
        const int rg = ((t >> 4) & 15) + (t & 15);
#pragma unroll 1
        for (int it = 0; it < 31; ++it)
            brow[it][t] = tab2[it - rg + 30];
    }
    __syncthreads();

    // phase 3: main loop
    const int w   = t >> 6;
    const int dl  = w & 1;
    const int gh  = w >> 1;
    const int hl  = t & 63;
    const int qi  = ((hl & 15) << 2) | (hl >> 4);  // bit-swizzled h-quad index
    const int h0  = qi * 4;
    const int rh0 = (qi >> 2) + 4 * (qi & 3);      // r(h0); r(h0+r)=rh0+r

    float q[4];
    {
        const float bb = qkv_b[d0 + dl];
        const float4 x4 = *(const float4*)(q0 + (size_t)(d0 + dl) * TOK + h0);
        q[0] = x4.x + bb; q[1] = x4.y + bb; q[2] = x4.z + bb; q[3] = x4.w + bb;
    }

    float l[4]  = {0.f, 0.f, 0.f, 0.f};
    float am[4] = {0.f, 0.f, 0.f, 0.f};

    const int pbeg = gh * 128;
#pragma unroll 2
    for (int p = pbeg; p < pbeg + 128; p += 4) {
        const float4 k4 = *(const float4*)&ks_[dl][p];   // wave-uniform (bcast)
        const float4 v4 = *(const float4*)&vs_[dl][p];
#pragma unroll
        for (int r = 0; r < 4; ++r) {
            const float2 b01 = *(const float2*)&brow[rh0 + r][p];
            const float2 b23 = *(const float2*)&brow[rh0 + r][p + 2];
            float e;
            e = EXP2(fmaf(q[r], k4.x, b01.x)); l[r] += e; am[r] = fmaf(e, v4.x, am[r]);
            e = EXP2(fmaf(q[r], k4.y, b01.y)); l[r] += e; am[r] = fmaf(e, v4.y, am[r]);
            e = EXP2(fmaf(q[r], k4.z, b23.x)); l[r] += e; am[r] = fmaf(e, v4.z, am[r]);
            e = EXP2(fmaf(q[r], k4.w, b23.y)); l[r] += e; am[r] = fmaf(e, v4.w, am[r]);
        }
    }

    // phase 4: merge g-halves, normalize, store as hi/lo planes (B-frag layout)
    if (gh == 1) {
        *(float4*)&lpart[dl][h0] = make_float4(l[0], l[1], l[2], l[3]);
        *(float4*)&apart[dl][h0] = make_float4(am[0], am[1], am[2], am[3]);
    }
    __syncthreads();
    if (gh == 0) {
        const float4 lo = *(const float4*)&lpart[dl][h0];
        const float4 ao = *(const float4*)&apart[dl][h0];
        float vals[4];
        vals[0] = (am[0] + ao.x) / (l[0] + lo.x);
        vals[1] = (am[1] + ao.y) / (l[1] + lo.y);
        vals[2] = (am[2] + ao.z) / (l[2] + lo.z);
        vals[3] = (am[3] + ao.w) / (l[3] + lo.w);
        const int d = d0 + dl;
        const size_t ob = (((size_t)b * 16 + (h0 >> 4)) * K8 + (d >> 3)) * 128
                          + (size_t)(h0 & 15) * 8 + (d & 7);
#pragma unroll
        for (int r = 0; r < 4; ++r) {
            const unsigned short hh = f2bf(vals[r]);
            aoh[ob + (size_t)r * 8] = hh;
            aol[ob + (size_t)r * 8] = f2bf(vals[r] - bf2f(hh));
        }
    }
}

// ---------------------------------------------------------------------------
extern "C" void kernel_launch(void* const* d_in, const int* in_sizes, int n_in,
                              void* d_out, int out_size, void* d_ws, size_t ws_size,
                              hipStream_t stream)
{
    const float* x      = (const float*)d_in[0];   // [2][512][256]
    const float* qkv_w  = (const float*)d_in[1];   // [1536][512]
    const float* qkv_b  = (const float*)d_in[2];   // [1536]
    const float* proj_w = (const float*)d_in[3];   // [512][512]
    const float* proj_b = (const float*)d_in[4];   // [512]
    const float* rpb    = (const float*)d_in[5];   // [961]
    float* out = (float*)d_out;                    // [2][512][256]

    unsigned short* U = (unsigned short*)d_ws;
    float* qkvf = (float*)d_ws + OFF_QKVF;

    // convert all GEMM operands once -> frag-tiled hi/lo planes (~2 us)
    prep<<<dim3(640), 256, 0, stream>>>(qkv_w, x, proj_w, U);

    // qkv = qkv_w @ x : M=1536, K=512 unsplit -> grid (48,4,2) = 384 waves
    gemm_frag<false><<<dim3(48, 4, 2), 64, 0, stream>>>(
        U + OFF_WQAH, U + OFF_WQAL, U + OFF_XBH, U + OFF_XBL,
        nullptr, qkvf, 1536);

    // fused attention: grid (d-pairs=256, b=2); writes aout planes for proj
    attn_f32<<<dim3(256, 2), 256, 0, stream>>>(qkvf, qkv_b, rpb,
                                               U + OFF_AOBH, U + OFF_AOBL);

    // out = proj_w @ aout + proj_b : M=512, K=512 -> grid (16,4,2) = 128 waves
    gemm_frag<true><<<dim3(16, 4, 2), 64, 0, stream>>>(
        U + OFF_WPAH, U + OFF_WPAL, U + OFF_AOBH, U + OFF_AOBL,
        proj_b, out, 512);
}

// Round 4
// 99.798 us; speedup vs baseline: 1.1621x; 1.1621x over previous
//
#include <hip/hip_runtime.h>

// Problem: B=2, DIM=512, NUM_HEADS=1, tokens TOK=256 (16x16 window, w=1).
// Pipeline (4 kernels):
//   prep      : convert qkv_w, x, proj_w -> bf16 hi/lo planes, MFMA-frag-tiled
//   gemm_frag : bf16 split-3 MFMA GEMM, 256-thr blocks, 4-wave INTRA-BLOCK
//               K-split + LDS cross-wave reduce (qkv -> fp32; proj -> out+bias)
//   attn_f32  : fused per-channel attention; epilogue writes aout as frag-tiled
//               hi/lo planes (proj's B operand)
//
// Frag-tiled layout for an MFMA operand (A: [M][K] rows=m; B: logical [K][N]
// consumed as [n][k]):  idx(r, k) = ((r/16)*(K/8) + k/8)*128 + (r%16)*8 + (k%8)
// A wave's fragment load (lr=lane&15 row, lg=lane>>4 k-chunk) is 64 lanes x 16B
// = one contiguous 1 KiB block -> perfect coalesce, L2-resident.
//
// R3 bug fixed here: reduce-store column base is nt0*16 (nt0 counts 16-col
// tiles), NOT nt0*64 — the *64 version wrote up to 768 cols OOB past d_out
// and caused the GPU memory-fault abort.
//
// ws layout: ushort planes first, then fp32 qkv buffer.
//   WqAh 0        WqAl 786432    (qkv_w planes, 1536x512)
//   XBh  1572864  XBl  1835008   (x planes,     2x[256n][512k])
//   WpAh 2097152  WpAl 2359296   (proj_w planes, 512x512)
//   AoBh 2621440  AoBl 2883584   (aout planes,  2x[256n][512k])
//   qkvf32 at float offset 1572864 (byte 6291456): [2][1536][256] fp32
// total 9.4 MB of d_ws.

#define TOK    256
#define KDIM   512
#define K8     64                   // KDIM/8
#define LOG2E  1.4426950408889634f
#define SCALE  0.04419417382415922f // 512^{-1/2}

#define OFF_WQAH 0
#define OFF_WQAL 786432
#define OFF_XBH  1572864
#define OFF_XBL  1835008
#define OFF_WPAH 2097152
#define OFF_WPAL 2359296
#define OFF_AOBH 2621440
#define OFF_AOBL 2883584
#define OFF_QKVF 1572864            // float offset

#define EXP2(x) __builtin_amdgcn_exp2f(x)

typedef __attribute__((ext_vector_type(8))) short short8_t;  // 8 bf16 (4 VGPR)
typedef __attribute__((ext_vector_type(4))) float f32x4;     // MFMA acc

// round-to-nearest-even fp32 -> bf16 bits
__device__ __forceinline__ unsigned short f2bf(float x) {
    unsigned int u = __float_as_uint(x);
    u += 0x7fffu + ((u >> 16) & 1u);
    return (unsigned short)(u >> 16);
}
__device__ __forceinline__ float bf2f(unsigned short h) {
    return __uint_as_float((unsigned int)h << 16);
}

__device__ __forceinline__ void cvt8(const float* v, unsigned short* hq,
                                     unsigned short* lq) {
#pragma unroll
    for (int j = 0; j < 8; ++j) {
        const unsigned short h = f2bf(v[j]);
        hq[j] = h;
        lq[j] = f2bf(v[j] - bf2f(h));
    }
}

// ---------------------------------------------------------------------------
// prep: one thread per 8-wide k-chunk. 163,840 threads = 640 blocks x 256.
//   job0 [0,98304):      qkv_w [1536][512] -> WqAh/WqAl (A-frag layout)
//   job1 [98304,131072): x [2][512][256]   -> XBh/XBl   (B-frag layout, n=tok)
//   job2 [131072,163840): proj_w [512][512] -> WpAh/WpAl
// ---------------------------------------------------------------------------
__global__ __launch_bounds__(256)
void prep(const float* __restrict__ qkv_w, const float* __restrict__ x,
          const float* __restrict__ proj_w, unsigned short* __restrict__ U)
{
    const int id = blockIdx.x * 256 + threadIdx.x;
    alignas(16) unsigned short hq[8], lq[8];
    float v[8];

    if (id < 98304) {                       // qkv_w
        const int m = id >> 6, kc = id & 63;
        const float* s = qkv_w + (size_t)m * KDIM + kc * 8;
#pragma unroll
        for (int j = 0; j < 8; ++j) v[j] = s[j];
        cvt8(v, hq, lq);
        const size_t o = ((size_t)(m >> 4) * K8 + kc) * 128 + (size_t)(m & 15) * 8;
        *(uint4*)(U + OFF_WQAH + o) = *(const uint4*)hq;
        *(uint4*)(U + OFF_WQAL + o) = *(const uint4*)lq;
    } else if (id < 131072) {               // x (transpose k<->n into B-frag)
        const int rid = id - 98304;
        const int n = rid & 255, kc = (rid >> 8) & 63, b = rid >> 14;
        const float* s = x + ((size_t)b * KDIM + kc * 8) * TOK + n;
#pragma unroll
        for (int j = 0; j < 8; ++j) v[j] = s[(size_t)j * TOK];
        cvt8(v, hq, lq);
        const size_t o = (((size_t)b * 16 + (n >> 4)) * K8 + kc) * 128
                         + (size_t)(n & 15) * 8;
        *(uint4*)(U + OFF_XBH + o) = *(const uint4*)hq;
        *(uint4*)(U + OFF_XBL + o) = *(const uint4*)lq;
    } else if (id < 163840) {               // proj_w
        const int rid = id - 131072;
        const int m = rid >> 6, kc = rid & 63;
        const float* s = proj_w + (size_t)m * KDIM + kc * 8;
#pragma unroll
        for (int j = 0; j < 8; ++j) v[j] = s[j];
        cvt8(v, hq, lq);
        const size_t o = ((size_t)(m >> 4) * K8 + kc) * 128 + (size_t)(m & 15) * 8;
        *(uint4*)(U + OFF_WPAH + o) = *(const uint4*)hq;
        *(uint4*)(U + OFF_WPAL + o) = *(const uint4*)lq;
    }
}

// ---------------------------------------------------------------------------
// Fragment GEMM, 256-thr blocks, intra-block K-split across the 4 waves.
// Block tile: (MT*16) m x 64 n. Wave w accumulates K-slice [128w, 128w+128)
// (4 K-steps of 32, ping-pong register prefetch), then the 4 partial tiles
// are summed through padded LDS (stride 68 -> conflict-free) and stored.
// Grid: (Mtot/(16*MT), TOK/64, 2).  qkv: MT=2 -> 384 blocks; proj: MT=1 -> 256.
// ---------------------------------------------------------------------------
template<int MT, bool BIAS>
__global__ __launch_bounds__(256)
void gemm_frag(const unsigned short* __restrict__ Ah,
               const unsigned short* __restrict__ Al,
               const unsigned short* __restrict__ Bh,
               const unsigned short* __restrict__ Bl,
               const float* __restrict__ bias,
               float* __restrict__ Cout, int Mtot)
{
    alignas(16) __shared__ float red[4][MT * 16][68];

    const int t    = threadIdx.x;
    const int w    = t >> 6;         // wave id = K-slice
    const int lane = t & 63;
    const int lr   = lane & 15;      // frag row (A) / col (B) / col (D)
    const int lg   = lane >> 4;      // k-chunk group / D row-quad
    const int mt0  = blockIdx.x * MT;
    const int nt0  = blockIdx.y * 4; // 16-col tile units
    const int b    = blockIdx.z;

    f32x4 acc[MT][4];
#pragma unroll
    for (int mi = 0; mi < MT; ++mi)
#pragma unroll
        for (int ni = 0; ni < 4; ++ni)
            acc[mi][ni] = (f32x4){0.f, 0.f, 0.f, 0.f};

    short8_t ah[2][MT], al[2][MT], bh[2][4], bl[2][4];

#define LDF(S, P) do {                                                        \
        const int kc_ = w * 16 + (S) * 4 + lg;                                \
        _Pragma("unroll")                                                     \
        for (int mi = 0; mi < MT; ++mi) {                                     \
            const size_t o_ = ((size_t)(mt0 + mi) * K8 + kc_) * 128           \
                              + (size_t)lr * 8;                               \
            ah[P][mi] = *(const short8_t*)(Ah + o_);                          \
            al[P][mi] = *(const short8_t*)(Al + o_);                          \
        }                                                                     \
        _Pragma("unroll")                                                     \
        for (int ni = 0; ni < 4; ++ni) {                                      \
            const size_t o_ = (((size_t)b * 16 + nt0 + ni) * K8 + kc_) * 128  \
                              + (size_t)lr * 8;                               \
            bh[P][ni] = *(const short8_t*)(Bh + o_);                          \
            bl[P][ni] = *(const short8_t*)(Bl + o_);                          \
        }                                                                     \
    } while (0)

    LDF(0, 0);
#pragma unroll
    for (int s = 0; s < 4; ++s) {            // 4 K-steps of 32 per wave
        const int p = s & 1;
        if (s + 1 < 4) LDF(s + 1, p ^ 1);    // prefetch next step's frags
#pragma unroll
        for (int mi = 0; mi < MT; ++mi)
#pragma unroll
            for (int ni = 0; ni < 4; ++ni) {
                acc[mi][ni] = __builtin_amdgcn_mfma_f32_16x16x32_bf16(
                    ah[p][mi], bh[p][ni], acc[mi][ni], 0, 0, 0);
                acc[mi][ni] = __builtin_amdgcn_mfma_f32_16x16x32_bf16(
                    al[p][mi], bh[p][ni], acc[mi][ni], 0, 0, 0);
                acc[mi][ni] = __builtin_amdgcn_mfma_f32_16x16x32_bf16(
                    ah[p][mi], bl[p][ni], acc[mi][ni], 0, 0, 0);
            }
    }
#undef LDF

    // cross-wave reduce: D frag (col=lr, row=lg*4+r) -> LDS -> sum -> global
#pragma unroll
    for (int mi = 0; mi < MT; ++mi)
#pragma unroll
        for (int ni = 0; ni < 4; ++ni)
#pragma unroll
            for (int r = 0; r < 4; ++r)
                red[w][mi * 16 + lg * 4 + r][ni * 16 + lr] = acc[mi][ni][r];
    __syncthreads();

#pragma unroll
    for (int it = 0; it < MT; ++it) {
        const int rr = it * 16 + (t >> 4);   // local row 0..MT*16-1
        const int cc = (t & 15) * 4;         // local col (float4)
        float4 v0 = *(const float4*)&red[0][rr][cc];
        const float4 v1 = *(const float4*)&red[1][rr][cc];
        const float4 v2 = *(const float4*)&red[2][rr][cc];
        const float4 v3 = *(const float4*)&red[3][rr][cc];
        v0.x += v1.x + v2.x + v3.x;
        v0.y += v1.y + v2.y + v3.y;
        v0.z += v1.z + v2.z + v3.z;
        v0.w += v1.w + v2.w + v3.w;
        const int grow = mt0 * 16 + rr;
        if (BIAS) {
            const float pb = bias[grow];
            v0.x += pb; v0.y += pb; v0.z += pb; v0.w += pb;
        }
        // column base = nt0*16 (nt0 in 16-col tile units) + cc  [R3 fix]
        *(float4*)(Cout + ((size_t)b * Mtot + grow) * TOK + nt0 * 16 + cc) = v0;
    }
}

// ---------------------------------------------------------------------------
// Fused per-channel attention. Block = 256 threads handles (b, d0..d0+1).
// Reads the unsplit fp32 qkv buffer [b][1536][256]; adds qkv bias inline.
// bias[h,g] = tab[r(h)-r(g)+30], r(h)=(h>>4)+(h&15): 61 distinct values,
// replicated into brow[31][258] (2-bank step, conflict-free float2 reads).
// Scores bounded (~1.1) -> no max-subtraction; g-half partials merge additively.
// Epilogue writes aout as hi/lo bf16 planes in proj's B-frag layout.
// ---------------------------------------------------------------------------
__global__ __launch_bounds__(256)
void attn_f32(const float* __restrict__ qkvf, const float* __restrict__ qkv_b,
              const float* __restrict__ rpb,
              unsigned short* __restrict__ aoh, unsigned short* __restrict__ aol)
{
    __shared__ float ks_[2][TOK];      // k * scale * log2e (incl. qkv bias)
    __shared__ float vs_[2][TOK];      // v (incl. qkv bias)
    __shared__ float tab2[64];         // rpb gathered, * log2e
    __shared__ float brow[31][258];    // bias rows, stride 258 (2-bank step)
    __shared__ float lpart[2][TOK];
    __shared__ float apart[2][TOK];

    const int t  = threadIdx.x;
    const int b  = blockIdx.y;
    const int d0 = blockIdx.x * 2;
    const float* q0 = qkvf + (size_t)b * (1536 * TOK);

    // phase 0: bias table (61 values)
    if (t < 61) {
        const int rel = t - 30;
        tab2[t] = rpb[rel < 0 ? rel + 961 : rel] * LOG2E;
    }
    // phase 1: stage k and v rows for the 2 channels (+qkv bias)
    {
        const int sel = t >> 7;          // 0: k, 1: v
        const int row = (t >> 6) & 1;    // dl
        const int g4  = (t & 63) * 4;
        const int o   = (sel ? 1024 : 512) + d0 + row;
        const float bb = qkv_b[o];
        float4 v = *(const float4*)(q0 + (size_t)o * TOK + g4);
        v.x += bb; v.y += bb; v.z += bb; v.w += bb;
        if (sel == 0) {
            const float s = SCALE * LOG2E;
            v.x *= s; v.y *= s; v.z *= s; v.w *= s;
            *(float4*)&ks_[row][g4] = v;
        } else {
            *(float4*)&vs_[row][g4] = v;
        }
    }
    __syncthreads();
    // phase 2: replicate bias into 31 rows x 256 g
    {
        const int rg = ((t >> 4) & 15) + (t & 15);
#pragma unroll 1
        for (int it = 0; it < 31; ++it)
            brow[it][t] = tab2[it - rg + 30];
    }
    __syncthreads();

    // phase 3: main loop
    const int w   = t >> 6;
    const int dl  = w & 1;
    const int gh  = w >> 1;
    const int hl  = t & 63;
    const int qi  = ((hl & 15) << 2) | (hl >> 4);  // bit-swizzled h-quad index
    const int h0  = qi * 4;
    const int rh0 = (qi >> 2) + 4 * (qi & 3);      // r(h0); r(h0+r)=rh0+r

    float q[4];
    {
        const float bb = qkv_b[d0 + dl];
        const float4 x4 = *(const float4*)(q0 + (size_t)(d0 + dl) * TOK + h0);
        q[0] = x4.x + bb; q[1] = x4.y + bb; q[2] = x4.z + bb; q[3] = x4.w + bb;
    }

    float l[4]  = {0.f, 0.f, 0.f, 0.f};
    float am[4] = {0.f, 0.f, 0.f, 0.f};

    const int pbeg = gh * 128;
#pragma unroll 2
    for (int p = pbeg; p < pbeg + 128; p += 4) {
        const float4 k4 = *(const float4*)&ks_[dl][p];   // wave-uniform (bcast)
        const float4 v4 = *(const float4*)&vs_[dl][p];
#pragma unroll
        for (int r = 0; r < 4; ++r) {
            const float2 b01 = *(const float2*)&brow[rh0 + r][p];
            const float2 b23 = *(const float2*)&brow[rh0 + r][p + 2];
            float e;
            e = EXP2(fmaf(q[r], k4.x, b01.x)); l[r] += e; am[r] = fmaf(e, v4.x, am[r]);
            e = EXP2(fmaf(q[r], k4.y, b01.y)); l[r] += e; am[r] = fmaf(e, v4.y, am[r]);
            e = EXP2(fmaf(q[r], k4.z, b23.x)); l[r] += e; am[r] = fmaf(e, v4.z, am[r]);
            e = EXP2(fmaf(q[r], k4.w, b23.y)); l[r] += e; am[r] = fmaf(e, v4.w, am[r]);
        }
    }

    // phase 4: merge g-halves, normalize, store as hi/lo planes (B-frag layout)
    if (gh == 1) {
        *(float4*)&lpart[dl][h0] = make_float4(l[0], l[1], l[2], l[3]);
        *(float4*)&apart[dl][h0] = make_float4(am[0], am[1], am[2], am[3]);
    }
    __syncthreads();
    if (gh == 0) {
        const float4 lo = *(const float4*)&lpart[dl][h0];
        const float4 ao = *(const float4*)&apart[dl][h0];
        float vals[4];
        vals[0] = (am[0] + ao.x) / (l[0] + lo.x);
        vals[1] = (am[1] + ao.y) / (l[1] + lo.y);
        vals[2] = (am[2] + ao.z) / (l[2] + lo.z);
        vals[3] = (am[3] + ao.w) / (l[3] + lo.w);
        const int d = d0 + dl;
        const size_t ob = (((size_t)b * 16 + (h0 >> 4)) * K8 + (d >> 3)) * 128
                          + (size_t)(h0 & 15) * 8 + (d & 7);
#pragma unroll
        for (int r = 0; r < 4; ++r) {
            const unsigned short hh = f2bf(vals[r]);
            aoh[ob + (size_t)r * 8] = hh;
            aol[ob + (size_t)r * 8] = f2bf(vals[r] - bf2f(hh));
        }
    }
}

// ---------------------------------------------------------------------------
extern "C" void kernel_launch(void* const* d_in, const int* in_sizes, int n_in,
                              void* d_out, int out_size, void* d_ws, size_t ws_size,
                              hipStream_t stream)
{
    const float* x      = (const float*)d_in[0];   // [2][512][256]
    const float* qkv_w  = (const float*)d_in[1];   // [1536][512]
    const float* qkv_b  = (const float*)d_in[2];   // [1536]
    const float* proj_w = (const float*)d_in[3];   // [512][512]
    const float* proj_b = (const float*)d_in[4];   // [512]
    const float* rpb    = (const float*)d_in[5];   // [961]
    float* out = (float*)d_out;                    // [2][512][256]

    unsigned short* U = (unsigned short*)d_ws;
    float* qkvf = (float*)d_ws + OFF_QKVF;

    // convert all GEMM operands once -> frag-tiled hi/lo planes
    prep<<<dim3(640), 256, 0, stream>>>(qkv_w, x, proj_w, U);

    // qkv = qkv_w @ x : MT=2 -> grid (48,4,2) = 384 blocks x 4 waves
    gemm_frag<2, false><<<dim3(48, 4, 2), 256, 0, stream>>>(
        U + OFF_WQAH, U + OFF_WQAL, U + OFF_XBH, U + OFF_XBL,
        nullptr, qkvf, 1536);

    // fused attention: grid (d-pairs=256, b=2); writes aout planes for proj
    attn_f32<<<dim3(256, 2), 256, 0, stream>>>(qkvf, qkv_b, rpb,
                                               U + OFF_AOBH, U + OFF_AOBL);

    // out = proj_w @ aout + proj_b : MT=1 -> grid (32,4,2) = 256 blocks
    gemm_frag<1, true><<<dim3(32, 4, 2), 256, 0, stream>>>(
        U + OFF_WPAH, U + OFF_WPAL, U + OFF_AOBH, U + OFF_AOBL,
        proj_b, out, 512);
}